// Round 7
// baseline (330.427 us; speedup 1.0000x reference)
//
#include <hip/hip_runtime.h>

#define HID 10
#define STEPS 512

typedef __attribute__((ext_vector_type(2))) float v2f;

// broadcast lane ((lane&0x30)|F) within each 16-lane group (BitMode: and=0x10 keeps
// bit4, or=F sets low bits; bit5 preserved implicitly per 32-lane half)
template<int F>
static __device__ __forceinline__ float swz(float v) {
    return __int_as_float(__builtin_amdgcn_ds_swizzle(__float_as_int(v), (F << 5) | 0x10));
}

// forced packed-fp32 math (backend scalarized <2 x float> ops in round 6)
static __device__ __forceinline__ v2f pk_mul(v2f a, v2f b) {
    v2f d;
    asm("v_pk_mul_f32 %0, %1, %2" : "=v"(d) : "v"(a), "v"(b));
    return d;
}
static __device__ __forceinline__ void pk_fma(v2f& acc, v2f a, v2f b) {
    asm("v_pk_fma_f32 %0, %1, %2, %0" : "+v"(acc) : "v"(a), "v"(b));
}

// Lane-parallel fused GRU decoder: 1 feature/lane, 4 batches/wave, 2048 waves (2/SIMD).
// k-packed dots via v_pk_fma_f32; output staged in LDS per 16-step window and flushed
// as full-128B-segment nontemporal stores (kills write-allocate RFO seen in round 6).
__global__ __launch_bounds__(64, 2) void gru_decoder_kernel(
    const float* __restrict__ hidden, const float* __restrict__ w_ih,
    const float* __restrict__ w_hh, const float* __restrict__ b_ih,
    const float* __restrict__ b_hh, const float* __restrict__ l1_w,
    const float* __restrict__ l1_b, const float* __restrict__ l2_w,
    const float* __restrict__ l2_b, float* __restrict__ out)
{
    __shared__ float sWx[640];   // l2_w @ l1_w (64x10)
    __shared__ float sbx[64];    // l2_w @ l1_b + l2_b
    __shared__ float sWgi[300];  // w_ih @ Wx (30x10)
    __shared__ float sbgi[30];   // b_ih + w_ih @ bx
    __shared__ float sWhh[300];  // w_hh copy (t=0 peel)
    __shared__ alignas(16) float sstage[4 * 168];  // per-group o staging: 160 data + trash

    const int lane = threadIdx.x;
    const int f    = lane & 15;
    const int grp  = lane >> 4;
    const int b    = blockIdx.x * 4 + grp;
    const bool ok  = (f < HID);
    const int fi   = ok ? f : 0;

    // ---- preamble: fused weights (fp32, cooperative) ----
    for (int e = lane; e < 640; e += 64) {
        int i = e / 10, j = e - i * 10;
        float acc = 0.f;
        #pragma unroll
        for (int k = 0; k < 10; ++k) acc += l2_w[i * 10 + k] * l1_w[k * 10 + j];
        sWx[e] = acc;
    }
    {
        float acc = l2_b[lane];
        #pragma unroll
        for (int k = 0; k < 10; ++k) acc += l2_w[lane * 10 + k] * l1_b[k];
        sbx[lane] = acc;
    }
    for (int e = lane; e < 300; e += 64) sWhh[e] = w_hh[e];
    __syncthreads();
    for (int e = lane; e < 300; e += 64) {
        int m = e / 10, j = e - m * 10;
        float acc = 0.f;
        for (int k = 0; k < 64; ++k) acc += w_ih[m * 64 + k] * sWx[k * 10 + j];
        sWgi[e] = acc;
    }
    if (lane < 30) {
        float acc = b_ih[lane];
        for (int k = 0; k < 64; ++k) acc += w_ih[lane * 64 + k] * sbx[k];
        sbgi[lane] = acc;
    }
    __syncthreads();

    const float LOG2E = 1.4426950408889634f;
    const float S2    = 2.f * LOG2E;

    // ---- per-lane weights, k-packed pairs (feature fi; f>=10 zeroed) ----
    v2f wr2[5], wz2[5], wni2[5], wnh2[5], wo2[5];
    #pragma unroll
    for (int i = 0; i < 5; ++i) {
        int k0 = 2 * i, k1 = 2 * i + 1;
        if (ok) {
            wr2[i]  = (v2f){-(sWgi[fi * 10 + k0] + sWhh[fi * 10 + k0]) * LOG2E,
                            -(sWgi[fi * 10 + k1] + sWhh[fi * 10 + k1]) * LOG2E};
            wz2[i]  = (v2f){-(sWgi[(10 + fi) * 10 + k0] + sWhh[(10 + fi) * 10 + k0]) * LOG2E,
                            -(sWgi[(10 + fi) * 10 + k1] + sWhh[(10 + fi) * 10 + k1]) * LOG2E};
            wni2[i] = (v2f){sWgi[(20 + fi) * 10 + k0] * S2, sWgi[(20 + fi) * 10 + k1] * S2};
            wnh2[i] = (v2f){sWhh[(20 + fi) * 10 + k0] * S2, sWhh[(20 + fi) * 10 + k1] * S2};
            wo2[i]  = (v2f){l1_w[fi * 10 + k0], l1_w[fi * 10 + k1]};
        } else {
            v2f zz = {0.f, 0.f};
            wr2[i] = zz; wz2[i] = zz; wni2[i] = zz; wnh2[i] = zz; wo2[i] = zz;
        }
    }
    const float br  = ok ? -(sbgi[fi] + b_hh[fi]) * LOG2E : 0.f;
    const float bz  = ok ? -(sbgi[10 + fi] + b_hh[10 + fi]) * LOG2E : 0.f;
    const float bni = ok ? sbgi[20 + fi] * S2 : 0.f;
    const float bnh = ok ? b_hh[20 + fi] * S2 : 0.f;
    const float bo  = ok ? l1_b[fi] : 0.f;
    const float br0  = ok ? -(b_ih[fi] + b_hh[fi]) * LOG2E : 0.f;
    const float bz0  = ok ? -(b_ih[10 + fi] + b_hh[10 + fi]) * LOG2E : 0.f;
    const float bni0 = ok ? b_ih[20 + fi] * S2 : 0.f;

    // ---- initial h (one feature per lane; f>=10 stays exactly 0) ----
    float h = ok ? hidden[(size_t)b * HID + f] : 0.f;

    v2f h2[5];
    #define GATHER()                                             \
        h2[0] = (v2f){swz<0>(h), swz<1>(h)};                     \
        h2[1] = (v2f){swz<2>(h), swz<3>(h)};                     \
        h2[2] = (v2f){swz<4>(h), swz<5>(h)};                     \
        h2[3] = (v2f){swz<6>(h), swz<7>(h)};                     \
        h2[4] = (v2f){swz<8>(h), swz<9>(h)};

    GATHER();

    // ---- output staging pointers ----
    // wp: per-step LDS slot (15-s)*10+f for data lanes, dump slot 166 for trash lanes
    float* wp = ok ? &sstage[grp * 168 + 150 + f] : &sstage[grp * 168 + 166];
    const int vdec = ok ? 10 : 0;          // per-step wp decrement (trash lanes pinned)
    const int vinc = vdec * 16;            // per-flush wp rewind
    // pf: per-lane global flush pointer (2 dwords per lane, 5 chunks of 32 dwords)
    float* pf = out + (size_t)b * (STEPS * HID) + (size_t)(STEPS - 16) * HID + 2 * f;
    const int rb = grp * 168 + 2 * f;      // flush LDS read base (dwords)

    #define O_WRITE()                                            \
        {                                                        \
            v2f ao = pk_mul(wo2[0], h2[0]);                      \
            pk_fma(ao, wo2[1], h2[1]);                           \
            pk_fma(ao, wo2[2], h2[2]);                           \
            pk_fma(ao, wo2[3], h2[3]);                           \
            pk_fma(ao, wo2[4], h2[4]);                           \
            *wp = ao.x + ao.y + bo;                              \
            wp -= vdec;                                          \
        }

    // ---- t = 0 peeled: gi = b_ih only (x_0 = 0); raw w_hh dots from LDS ----
    {
        float ha[10];
        #pragma unroll
        for (int i = 0; i < 5; ++i) { ha[2 * i] = h2[i].x; ha[2 * i + 1] = h2[i].y; }
        float pr = 0.f, pz = 0.f, ph = 0.f;
        #pragma unroll
        for (int k = 0; k < 10; ++k) {
            pr += sWhh[fi * 10 + k] * ha[k];
            pz += sWhh[(10 + fi) * 10 + k] * ha[k];
            ph += sWhh[(20 + fi) * 10 + k] * ha[k];
        }
        float vr = br0 - pr * LOG2E;
        float vz = bz0 - pz * LOG2E;
        float r = __builtin_amdgcn_rcpf(1.f + __builtin_amdgcn_exp2f(vr));
        float z = __builtin_amdgcn_rcpf(1.f + __builtin_amdgcn_exp2f(vz));
        float y = bni0 + r * (ph * S2 + bnh);
        float n = 1.f - 2.f * __builtin_amdgcn_rcpf(1.f + __builtin_amdgcn_exp2f(y));
        h = ok ? (n + z * (h - n)) : 0.f;
        GATHER();
        O_WRITE();
    }

    // ---- t = 1 .. 511; flush every 16 steps as full-segment nt stores ----
    #pragma unroll 1
    for (int t = 1; t < STEPS; ++t) {
        v2f ar = pk_mul(wr2[0], h2[0]);
        v2f az = pk_mul(wz2[0], h2[0]);
        v2f ai = pk_mul(wni2[0], h2[0]);
        v2f ah = pk_mul(wnh2[0], h2[0]);
        #pragma unroll
        for (int i = 1; i < 5; ++i) {
            pk_fma(ar, wr2[i], h2[i]);
            pk_fma(az, wz2[i], h2[i]);
            pk_fma(ai, wni2[i], h2[i]);
            pk_fma(ah, wnh2[i], h2[i]);
        }
        float vr = (ar.x + ar.y) + br;
        float vz = (az.x + az.y) + bz;
        float r = __builtin_amdgcn_rcpf(1.f + __builtin_amdgcn_exp2f(vr));
        float z = __builtin_amdgcn_rcpf(1.f + __builtin_amdgcn_exp2f(vz));
        float y = ((ai.x + ai.y) + bni) + r * ((ah.x + ah.y) + bnh);
        float n = 1.f - 2.f * __builtin_amdgcn_rcpf(1.f + __builtin_amdgcn_exp2f(y));
        h = n + z * (h - n);          // f>=10: zero weights/biases keep h == 0
        GATHER();
        O_WRITE();

        if ((t & 15) == 15) {         // wave-uniform, 1-in-16
            #pragma unroll
            for (int c = 0; c < 5; ++c) {
                v2f v = *reinterpret_cast<const v2f*>(&sstage[rb + 32 * c]);
                __builtin_nontemporal_store(v, reinterpret_cast<v2f*>(pf + 32 * c));
            }
            pf -= 16 * HID;
            wp += vinc;
        }
    }
}

extern "C" void kernel_launch(void* const* d_in, const int* in_sizes, int n_in,
                              void* d_out, int out_size, void* d_ws, size_t ws_size,
                              hipStream_t stream) {
    (void)in_sizes; (void)n_in; (void)d_ws; (void)ws_size; (void)out_size;
    dim3 grid(2048), block(64);   // 4 batches/wave, 2048 waves -> 2 waves per SIMD
    gru_decoder_kernel<<<grid, block, 0, stream>>>(
        (const float*)d_in[0], (const float*)d_in[1], (const float*)d_in[2],
        (const float*)d_in[3], (const float*)d_in[4], (const float*)d_in[5],
        (const float*)d_in[6], (const float*)d_in[7], (const float*)d_in[8],
        (float*)d_out);
}